// Round 4
// baseline (594.769 us; speedup 1.0000x reference)
//
#include <hip/hip_runtime.h>
#include <math.h>

typedef unsigned short u16;
typedef short s16x8 __attribute__((ext_vector_type(8)));
typedef float f32x4 __attribute__((ext_vector_type(4)));

#define MFMA16(a, b, c) __builtin_amdgcn_mfma_f32_16x16x32_bf16((a), (b), (c), 0, 0, 0)

__device__ __forceinline__ u16 f2b(float f) {
  unsigned u = __float_as_uint(f);
  unsigned r = (u + 0x7fff + ((u >> 16) & 1)) >> 16;
  return (u16)r;
}
__device__ __forceinline__ float b2f(u16 h) { return __uint_as_float(((unsigned)h) << 16); }

// ---------------- LayerNorm -> bf16 ----------------
__global__ __launch_bounds__(256) void ln_kernel(const float* __restrict__ x, const float* __restrict__ w,
                          const float* __restrict__ b, u16* __restrict__ xn) {
  int row = blockIdx.x;
  const float* xr = x + (size_t)row * 512;
  int t = threadIdx.x;
  float v0 = xr[t], v1 = xr[t + 256];
  float s = v0 + v1, ss = v0*v0 + v1*v1;
  for (int o = 32; o > 0; o >>= 1) { s += __shfl_down(s, o); ss += __shfl_down(ss, o); }
  __shared__ float ls[4], lss[4];
  int wid = t >> 6, lane = t & 63;
  if (lane == 0) { ls[wid] = s; lss[wid] = ss; }
  __syncthreads();
  float tot  = ls[0]+ls[1]+ls[2]+ls[3];
  float tot2 = lss[0]+lss[1]+lss[2]+lss[3];
  float mean = tot * (1.f/512);
  float var  = tot2 * (1.f/512) - mean*mean;
  float inv = rsqrtf(var + 1e-5f);
  u16* xo = xn + (size_t)row * 512;
  xo[t]     = f2b((v0-mean)*inv*w[t]     + b[t]);
  xo[t+256] = f2b((v1-mean)*inv*w[t+256] + b[t+256]);
}

// ---------------- weight transpose + cast ----------------
__global__ __launch_bounds__(256) void wcast_T(const float* __restrict__ W, u16* __restrict__ WT, int R, int C) {
  int idx = blockIdx.x*256 + threadIdx.x;
  if (idx >= R*C) return;
  int r = idx / C, c = idx - r*C;
  WT[(size_t)c*R + r] = f2b(W[idx]);
}

// ---------------- v transpose ----------------
__global__ __launch_bounds__(256) void vtrans(const u16* __restrict__ v, u16* __restrict__ vT) {
  __shared__ u16 tile[64][72];
  int bh = blockIdx.y, n0 = blockIdx.x * 64;
  int t = threadIdx.x;
  const u16* vb = v + ((size_t)bh*4096 + n0)*64;
  #pragma unroll
  for (int p = 0; p < 2; p++) {
    int c = t + p*256;
    int r = c >> 3, col = (c & 7)*8;
    *(uint4*)&tile[r][col] = *(const uint4*)&vb[(size_t)r*64 + col];
  }
  __syncthreads();
  #pragma unroll
  for (int p = 0; p < 2; p++) {
    int c = t + p*256;
    int d = c >> 3, ncol = (c & 7)*8;
    u16 tmp[8];
    #pragma unroll
    for (int j = 0; j < 8; j++) tmp[j] = tile[ncol + j][d];
    *(uint4*)&vT[((size_t)bh*64 + d)*4096 + n0 + ncol] = *(uint4*)tmp;
  }
}

// ---------------- 128x128 MFMA GEMM core, BK=64 with register prefetch ----------------
__device__ __forceinline__ void gemm128_core64(const u16* __restrict__ A, const u16* __restrict__ BT,
    int K, int ldA, int ldBT, int row0, int col0, u16* As, u16* Bs, f32x4 acc[4][4]) {
  int t = threadIdx.x, lane = t & 63, wid = t >> 6;
  int wr = (wid >> 1) * 64, wc = (wid & 1) * 64;
  int lr = lane & 15, lg = lane >> 4;
  uint4 pa[4], pb[4];
  #pragma unroll
  for (int p = 0; p < 4; p++) {
    int c = t + p*256, r = c >> 3, cc = (c & 7) * 8;
    pa[p] = *(const uint4*)&A[(size_t)(row0 + r)*ldA + cc];
    pb[p] = *(const uint4*)&BT[(size_t)(col0 + r)*ldBT + cc];
  }
  for (int k0 = 0; k0 < K; k0 += 64) {
    __syncthreads();
    #pragma unroll
    for (int p = 0; p < 4; p++) {
      int c = t + p*256, r = c >> 3, cc = (c & 7) * 8;
      *(uint4*)&As[r*72 + cc] = pa[p];
      *(uint4*)&Bs[r*72 + cc] = pb[p];
    }
    __syncthreads();
    if (k0 + 64 < K) {
      #pragma unroll
      for (int p = 0; p < 4; p++) {
        int c = t + p*256, r = c >> 3, cc = (c & 7) * 8;
        pa[p] = *(const uint4*)&A[(size_t)(row0 + r)*ldA + k0 + 64 + cc];
        pb[p] = *(const uint4*)&BT[(size_t)(col0 + r)*ldBT + k0 + 64 + cc];
      }
    }
    #pragma unroll
    for (int kk = 0; kk < 2; kk++) {
      s16x8 af[4], bf[4];
      #pragma unroll
      for (int f = 0; f < 4; f++) {
        af[f] = *(s16x8*)&As[(wr + f*16 + lr)*72 + kk*32 + lg*8];
        bf[f] = *(s16x8*)&Bs[(wc + f*16 + lr)*72 + kk*32 + lg*8];
      }
      #pragma unroll
      for (int i = 0; i < 4; i++)
        #pragma unroll
        for (int j = 0; j < 4; j++)
          acc[i][j] = MFMA16(af[i], bf[j], acc[i][j]);
    }
  }
}

// ---------------- QKV ----------------
__global__ __launch_bounds__(256) void qkv_mfma(const u16* __restrict__ xn, const u16* __restrict__ wT,
    u16* __restrict__ q, u16* __restrict__ k, u16* __restrict__ v) {
  __shared__ u16 As[128*72], Bs[128*72];
  f32x4 acc[4][4];
  #pragma unroll
  for (int i = 0; i < 4; i++)
    #pragma unroll
    for (int j = 0; j < 4; j++) acc[i][j] = (f32x4)0.f;
  int row0 = blockIdx.y*128, col0 = blockIdx.x*128;
  gemm128_core64(xn, wT, 512, 512, 512, row0, col0, As, Bs, acc);
  int t = threadIdx.x, lane = t & 63, wid = t >> 6, lr = lane & 15, lg = lane >> 4;
  int wr = (wid >> 1)*64, wc = (wid & 1)*64;
  #pragma unroll
  for (int i = 0; i < 4; i++)
    #pragma unroll
    for (int j = 0; j < 4; j++)
      #pragma unroll
      for (int r = 0; r < 4; r++) {
        int row = row0 + wr + i*16 + lg*4 + r;
        int col = col0 + wc + j*16 + lr;
        float val = acc[i][j][r];
        int part = col >> 9, rem = col & 511, h = rem >> 6, d = rem & 63;
        int b = row >> 12, n = row & 4095;
        size_t bh = (size_t)(b*8 + h);
        size_t dst = (bh*4096 + n)*64 + d;
        if (part == 0)      q[dst] = f2b(val * 0.125f);
        else if (part == 1) k[dst] = f2b(val);
        else                v[dst] = f2b(val);
      }
}

// ---------------- out GEMM ----------------
__global__ __launch_bounds__(256) void out_mfma(const u16* __restrict__ outh, const u16* __restrict__ wT,
    const float* __restrict__ bo, const float* __restrict__ x, float* __restrict__ out) {
  __shared__ u16 As[128*72], Bs[128*72];
  f32x4 acc[4][4];
  #pragma unroll
  for (int i = 0; i < 4; i++)
    #pragma unroll
    for (int j = 0; j < 4; j++) acc[i][j] = (f32x4)0.f;
  int row0 = blockIdx.y*128, col0 = blockIdx.x*128;
  gemm128_core64(outh, wT, 512, 512, 512, row0, col0, As, Bs, acc);
  int t = threadIdx.x, lane = t & 63, wid = t >> 6, lr = lane & 15, lg = lane >> 4;
  int wr = (wid >> 1)*64, wc = (wid & 1)*64;
  #pragma unroll
  for (int i = 0; i < 4; i++)
    #pragma unroll
    for (int j = 0; j < 4; j++)
      #pragma unroll
      for (int r = 0; r < 4; r++) {
        int row = row0 + wr + i*16 + lg*4 + r;
        int col = col0 + wc + j*16 + lr;
        size_t idx = (size_t)row*512 + col;
        out[idx] = x[idx] + acc[i][j][r] + bo[col];
      }
}

// ---------------- batched 64x64-tile MFMA GEMM with flexible epilogue ----------------
__global__ __launch_bounds__(256) void bmm64(const u16* __restrict__ A, const u16* __restrict__ BT,
    u16* __restrict__ Cn, u16* __restrict__ CT, u16* __restrict__ CE,
    int M, int N, int K, float alpha, float diag) {
  __shared__ u16 As[64*40], Bs[64*40];
  int batch = blockIdx.z;
  const u16* Ab = A  + (size_t)batch*M*K;
  const u16* Bb = BT + (size_t)batch*N*K;
  int row0 = blockIdx.y*64, col0 = blockIdx.x*64;
  int t = threadIdx.x, lane = t & 63, wid = t >> 6, lr = lane & 15, lg = lane >> 4;
  int wr = (wid >> 1)*32, wc = (wid & 1)*32;
  f32x4 acc[2][2];
  #pragma unroll
  for (int i = 0; i < 2; i++)
    #pragma unroll
    for (int j = 0; j < 2; j++) acc[i][j] = (f32x4)0.f;
  for (int k0 = 0; k0 < K; k0 += 32) {
    __syncthreads();
    int r = t >> 2, c = (t & 3)*8;
    *(uint4*)&As[r*40 + c] = *(const uint4*)&Ab[(size_t)(row0 + r)*K + k0 + c];
    *(uint4*)&Bs[r*40 + c] = *(const uint4*)&Bb[(size_t)(col0 + r)*K + k0 + c];
    __syncthreads();
    s16x8 af[2], bf[2];
    #pragma unroll
    for (int f = 0; f < 2; f++) {
      af[f] = *(s16x8*)&As[(wr + f*16 + lr)*40 + lg*8];
      bf[f] = *(s16x8*)&Bs[(wc + f*16 + lr)*40 + lg*8];
    }
    #pragma unroll
    for (int i = 0; i < 2; i++)
      #pragma unroll
      for (int j = 0; j < 2; j++)
        acc[i][j] = MFMA16(af[i], bf[j], acc[i][j]);
  }
  size_t cb = (size_t)batch*M*N;
  #pragma unroll
  for (int i = 0; i < 2; i++)
    #pragma unroll
    for (int j = 0; j < 2; j++)
      #pragma unroll
      for (int r = 0; r < 4; r++) {
        int row = row0 + wr + i*16 + lg*4 + r;
        int col = col0 + wc + j*16 + lr;
        float val = alpha*acc[i][j][r] + (row == col ? diag : 0.f);
        if (Cn) Cn[cb + (size_t)row*N + col] = f2b(val);
        if (CT) CT[cb + (size_t)col*M + row] = f2b(val);
        if (CE) CE[cb + (size_t)col*M + row] = f2b((row == col ? 7.f : 0.f) - val);
      }
}

// ---------------- landmarks ----------------
__global__ void landmark_kernel(const u16* __restrict__ q, const u16* __restrict__ k,
                                u16* __restrict__ ql, u16* __restrict__ kl) {
  int idx = blockIdx.x;
  int d = threadIdx.x;
  size_t base = ((size_t)idx * 16) * 64 + d;
  float sq = 0.f, sk = 0.f;
  #pragma unroll
  for (int j = 0; j < 16; j++) { sq += b2f(q[base + (size_t)j*64]); sk += b2f(k[base + (size_t)j*64]); }
  ql[(size_t)idx*64 + d] = f2b(sq * (1.f/16.f));
  kl[(size_t)idx*64 + d] = f2b(sk * (1.f/16.f));
}

// ---------------- sim2: MFMA QK^T + exact softmax + colsum-max (one block per bh) ----------------
__global__ __launch_bounds__(256) void sim2_mfma(const u16* __restrict__ ql, const u16* __restrict__ kl,
    float* __restrict__ a2, u16* __restrict__ a2h, unsigned* __restrict__ scal) {
  __shared__ u16 Qs[256*72];
  __shared__ u16 Ks2[256*72];
  __shared__ float wcol[4*256];
  __shared__ float red[256];
  int bh = blockIdx.x;
  int t = threadIdx.x, lane = t & 63, wid = t >> 6, lr = lane & 15, lg = lane >> 4;
  #pragma unroll
  for (int p = 0; p < 8; p++) {
    int c = t + p*256;
    int r = c >> 3, col = (c & 7)*8;
    *(uint4*)&Qs[r*72 + col]  = *(const uint4*)&ql[((size_t)bh*256 + r)*64 + col];
    *(uint4*)&Ks2[r*72 + col] = *(const uint4*)&kl[((size_t)bh*256 + r)*64 + col];
  }
  __syncthreads();
  float colp[16];
  #pragma unroll
  for (int cf = 0; cf < 16; cf++) colp[cf] = 0.f;
  for (int rf = 0; rf < 4; rf++) {
    int rbase = wid*64 + rf*16;
    s16x8 a0 = *(s16x8*)&Qs[(rbase + lr)*72 + lg*8];
    s16x8 a1 = *(s16x8*)&Qs[(rbase + lr)*72 + 32 + lg*8];
    f32x4 sf[16];
    #pragma unroll
    for (int cf = 0; cf < 16; cf++) {
      s16x8 b0 = *(s16x8*)&Ks2[(cf*16 + lr)*72 + lg*8];
      s16x8 b1 = *(s16x8*)&Ks2[(cf*16 + lr)*72 + 32 + lg*8];
      sf[cf] = MFMA16(a1, b1, MFMA16(a0, b0, (f32x4)0.f));
    }
    #pragma unroll
    for (int r = 0; r < 4; r++) {
      float mx = -3e38f;
      #pragma unroll
      for (int cf = 0; cf < 16; cf++) mx = fmaxf(mx, sf[cf][r]);
      #pragma unroll
      for (int o = 1; o < 16; o <<= 1) mx = fmaxf(mx, __shfl_xor(mx, o));
      float sum = 0.f;
      #pragma unroll
      for (int cf = 0; cf < 16; cf++) { sf[cf][r] = __expf(sf[cf][r] - mx); sum += sf[cf][r]; }
      #pragma unroll
      for (int o = 1; o < 16; o <<= 1) sum += __shfl_xor(sum, o);
      float inv = 1.f / sum;
      int row = rbase + lg*4 + r;
      size_t base = (size_t)bh*65536 + (size_t)row*256;
      #pragma unroll
      for (int cf = 0; cf < 16; cf++) {
        float pp = sf[cf][r] * inv;
        a2[base + cf*16 + lr] = pp;
        a2h[base + cf*16 + lr] = f2b(pp);
        colp[cf] += pp;
      }
    }
  }
  // reduce column partial sums: over lg groups, then waves
  #pragma unroll
  for (int cf = 0; cf < 16; cf++) {
    colp[cf] += __shfl_xor(colp[cf], 16);
    colp[cf] += __shfl_xor(colp[cf], 32);
  }
  if (lg == 0) {
    #pragma unroll
    for (int cf = 0; cf < 16; cf++) wcol[wid*256 + cf*16 + lr] = colp[cf];
  }
  __syncthreads();
  red[t] = wcol[t] + wcol[256 + t] + wcol[512 + t] + wcol[768 + t];
  __syncthreads();
  for (int o = 128; o > 0; o >>= 1) {
    if (t < o) red[t] = fmaxf(red[t], red[t+o]);
    __syncthreads();
  }
  if (t == 0) atomicMax(scal + 1, __float_as_uint(red[0]));
}

// ---------------- z0 = a2^T / colmax  (rowsum max == 1 exactly for softmax) ----------------
__global__ void z0_kernel(const float* __restrict__ a2, const unsigned* __restrict__ scal,
                          u16* __restrict__ zA, u16* __restrict__ zAT) {
  size_t idx = (size_t)blockIdx.x*256 + threadIdx.x;
  float inv = 1.f / __uint_as_float(scal[1]);
  size_t bh = idx >> 16; int rem = (int)(idx & 65535); int i = rem >> 8, j = rem & 255;
  zA[idx]  = f2b(a2[(bh<<16) + ((size_t)j<<8) + i] * inv);
  zAT[idx] = f2b(a2[idx] * inv);
}

// ---------------- split-K flash partials ----------------
__global__ __launch_bounds__(256) void flash_part(const u16* __restrict__ Q, const u16* __restrict__ Kg,
    const u16* __restrict__ VT, float* __restrict__ po, float* __restrict__ pm, float* __restrict__ pl) {
  __shared__ u16 Ks[64*72];
  __shared__ u16 Vs[64*72];
  __shared__ u16 Ps[4*16*72];
  int qt = blockIdx.x, ch = blockIdx.y, bh = blockIdx.z;
  int q0 = qt * 64;
  int t = threadIdx.x, lane = t & 63, wid = t >> 6, lr = lane & 15, lg = lane >> 4;
  const u16* Qb  = Q  + ((size_t)bh*256)*64;
  const u16* Kb  = Kg + ((size_t)bh*4096 + ch*512)*64;
  const u16* VTb = VT + ((size_t)bh*64)*4096 + ch*512;
  int qrow = q0 + wid*16 + lr;
  s16x8 aq0 = *(const s16x8*)&Qb[(size_t)qrow*64 + lg*8];
  s16x8 aq1 = *(const s16x8*)&Qb[(size_t)qrow*64 + 32 + lg*8];
  f32x4 oacc[4];
  #pragma unroll
  for (int f = 0; f < 4; f++) oacc[f] = (f32x4)0.f;
  float m_[4] = {-3e38f, -3e38f, -3e38f, -3e38f};
  float l_[4] = {0.f, 0.f, 0.f, 0.f};
  u16* Pw = Ps + wid*16*72;
  for (int k0 = 0; k0 < 512; k0 += 64) {
    __syncthreads();
    #pragma unroll
    for (int p = 0; p < 2; p++) {
      int c = t + p*256; int r = c >> 3, cc = (c & 7)*8;
      *(uint4*)&Ks[r*72 + cc] = *(const uint4*)&Kb[(size_t)(k0 + r)*64 + cc];
      *(uint4*)&Vs[r*72 + cc] = *(const uint4*)&VTb[(size_t)r*4096 + k0 + cc];
    }
    __syncthreads();
    f32x4 sf[4];
    #pragma unroll
    for (int f = 0; f < 4; f++) {
      s16x8 b0 = *(s16x8*)&Ks[(f*16 + lr)*72 + lg*8];
      s16x8 b1 = *(s16x8*)&Ks[(f*16 + lr)*72 + 32 + lg*8];
      f32x4 s = (f32x4)0.f;
      s = MFMA16(aq0, b0, s);
      s = MFMA16(aq1, b1, s);
      sf[f] = s;
    }
    #pragma unroll
    for (int r = 0; r < 4; r++) {
      float mx = fmaxf(fmaxf(sf[0][r], sf[1][r]), fmaxf(sf[2][r], sf[3][r]));
      #pragma unroll
      for (int o = 1; o < 16; o <<= 1) mx = fmaxf(mx, __shfl_xor(mx, o));
      float mn = fmaxf(m_[r], mx);
      float sum = 0.f;
      #pragma unroll
      for (int f = 0; f < 4; f++) {
        float pv = __expf(sf[f][r] - mn);
        sum += pv;
        Pw[(lg*4 + r)*72 + f*16 + lr] = f2b(pv);
      }
      #pragma unroll
      for (int o = 1; o < 16; o <<= 1) sum += __shfl_xor(sum, o);
      float sc = __expf(m_[r] - mn);
      l_[r] = l_[r]*sc + sum;
      m_[r] = mn;
      #pragma unroll
      for (int f = 0; f < 4; f++) oacc[f][r] *= sc;
    }
    __syncthreads();
    #pragma unroll
    for (int ks = 0; ks < 2; ks++) {
      s16x8 ap = *(s16x8*)&Pw[lr*72 + ks*32 + lg*8];
      #pragma unroll
      for (int df = 0; df < 4; df++) {
        s16x8 bv = *(s16x8*)&Vs[(df*16 + lr)*72 + ks*32 + lg*8];
        oacc[df] = MFMA16(ap, bv, oacc[df]);
      }
    }
  }
  int pidx = (bh*4 + qt)*8 + ch;
  #pragma unroll
  for (int r = 0; r < 4; r++) {
    int lrow = wid*16 + lg*4 + r;
    if (lr == 0) { pm[pidx*64 + lrow] = m_[r]; pl[pidx*64 + lrow] = l_[r]; }
    #pragma unroll
    for (int df = 0; df < 4; df++)
      po[((size_t)pidx*64 + lrow)*64 + df*16 + lr] = oacc[df][r];
  }
}

// ---------------- merge partials ----------------
__global__ __launch_bounds__(256) void flash_merge(const float* __restrict__ po, const float* __restrict__ pm,
    const float* __restrict__ pl, u16* __restrict__ a3vT) {
  int row = blockIdx.x*4 + (threadIdx.x >> 6);
  int d = threadIdx.x & 63;
  int bh = row >> 8, qrow = row & 255, qt = qrow >> 6, lrow = qrow & 63;
  int pbase = (bh*4 + qt)*8;
  float m = -3e38f;
  #pragma unroll
  for (int ch = 0; ch < 8; ch++) m = fmaxf(m, pm[(pbase+ch)*64 + lrow]);
  float L = 0.f, O = 0.f;
  #pragma unroll
  for (int ch = 0; ch < 8; ch++) {
    float w = __expf(pm[(pbase+ch)*64 + lrow] - m);
    L += w * pl[(pbase+ch)*64 + lrow];
    O += w * po[((size_t)(pbase+ch)*64 + lrow)*64 + d];
  }
  a3vT[((size_t)bh*64 + d)*256 + qrow] = f2b(O / L);
}

// ---------------- exact-softmax flash: outh = softmax(q @ kl^T) @ w2 ----------------
__global__ __launch_bounds__(256) void flash_a1(const u16* __restrict__ Q, const u16* __restrict__ Kl,
    const u16* __restrict__ W2T, u16* __restrict__ outh) {
  __shared__ u16 Ks[64*72];
  __shared__ u16 Vs[64*264];
  __shared__ u16 Ps[4*16*264];
  int bh = blockIdx.y;
  int q0 = blockIdx.x * 64;
  int t = threadIdx.x, lane = t & 63, wid = t >> 6, lr = lane & 15, lg = lane >> 4;
  const u16* Qb = Q + ((size_t)bh*4096)*64;
  #pragma unroll
  for (int p = 0; p < 8; p++) {
    int c = t + p*256; int r = c >> 5, col = (c & 31)*8;
    *(uint4*)&Vs[r*264 + col] = *(const uint4*)&W2T[((size_t)bh*64 + r)*256 + col];
  }
  int qrow = q0 + wid*16 + lr;
  s16x8 aq0 = *(const s16x8*)&Qb[(size_t)qrow*64 + lg*8];
  s16x8 aq1 = *(const s16x8*)&Qb[(size_t)qrow*64 + 32 + lg*8];
  f32x4 sf[16];
  #pragma unroll
  for (int f = 0; f < 16; f++) sf[f] = (f32x4)0.f;
  #pragma unroll
  for (int kt = 0; kt < 4; kt++) {
    __syncthreads();
    #pragma unroll
    for (int p = 0; p < 2; p++) {
      int c = t + p*256; int r = c >> 3, cc = (c & 7)*8;
      *(uint4*)&Ks[r*72 + cc] = *(const uint4*)&Kl[((size_t)bh*256 + kt*64 + r)*64 + cc];
    }
    __syncthreads();
    #pragma unroll
    for (int f2 = 0; f2 < 4; f2++) {
      s16x8 b0 = *(s16x8*)&Ks[(f2*16 + lr)*72 + lg*8];
      s16x8 b1 = *(s16x8*)&Ks[(f2*16 + lr)*72 + 32 + lg*8];
      sf[kt*4 + f2] = MFMA16(aq1, b1, MFMA16(aq0, b0, sf[kt*4 + f2]));
    }
  }
  u16* Pw = Ps + wid*16*264;
  float linv[4];
  #pragma unroll
  for (int r = 0; r < 4; r++) {
    float mx = -3e38f;
    #pragma unroll
    for (int f = 0; f < 16; f++) mx = fmaxf(mx, sf[f][r]);
    #pragma unroll
    for (int o = 1; o < 16; o <<= 1) mx = fmaxf(mx, __shfl_xor(mx, o));
    float sum = 0.f;
    #pragma unroll
    for (int f = 0; f < 16; f++) {
      float pv = __expf(sf[f][r] - mx);
      sum += pv;
      Pw[(lg*4 + r)*264 + f*16 + lr] = f2b(pv);
    }
    #pragma unroll
    for (int o = 1; o < 16; o <<= 1) sum += __shfl_xor(sum, o);
    linv[r] = 1.f / sum;
  }
  f32x4 oacc[4];
  #pragma unroll
  for (int f = 0; f < 4; f++) oacc[f] = (f32x4)0.f;
  #pragma unroll
  for (int ks = 0; ks < 8; ks++) {
    s16x8 ap = *(s16x8*)&Pw[lr*264 + ks*32 + lg*8];
    #pragma unroll
    for (int df = 0; df < 4; df++) {
      s16x8 bv = *(s16x8*)&Vs[(df*16 + lr)*264 + ks*32 + lg*8];
      oacc[df] = MFMA16(ap, bv, oacc[df]);
    }
  }
  int b = bh >> 3, h = bh & 7;
  #pragma unroll
  for (int df = 0; df < 4; df++)
    #pragma unroll
    for (int r = 0; r < 4; r++) {
      int lrow = wid*16 + lg*4 + r;
      int col = df*16 + lr;
      outh[((size_t)(b*4096 + q0 + lrow))*512 + h*64 + col] = f2b(oacc[df][r] * linv[r]);
    }
}

// ---------------- LDS-tiled residual depthwise conv, add into outh ----------------
__global__ __launch_bounds__(256) void conv_lds(const u16* __restrict__ v, const float* __restrict__ rw,
                                                u16* __restrict__ outh) {
  __shared__ u16 tile[160*72];
  __shared__ float wsm[33];
  int bh = blockIdx.y;
  int n0 = blockIdx.x * 128;
  int b = bh >> 3, h = bh & 7;
  int t = threadIdx.x;
  if (t < 33) wsm[t] = rw[h*33 + t];
  const u16* vb = v + ((size_t)bh*4096)*64;
  #pragma unroll
  for (int p = 0; p < 5; p++) {
    int c = t + p*256;               // 1280 uint4 chunks = 160 rows x 8
    int r = c >> 3, col = (c & 7)*8;
    int nn = n0 - 16 + r;
    uint4 val = make_uint4(0u,0u,0u,0u);
    if (nn >= 0 && nn < 4096) val = *(const uint4*)&vb[(size_t)nn*64 + col];
    *(uint4*)&tile[r*72 + col] = val;
  }
  __syncthreads();
  int d8 = (t & 7) * 8;
  int r0 = t >> 3;                   // 32 rows per pass
  #pragma unroll
  for (int pass = 0; pass < 4; pass++) {
    int lrow = pass*32 + r0;         // output row n0+lrow ; window tile rows lrow..lrow+32
    float acc[8] = {};
    #pragma unroll
    for (int j = 0; j < 33; j++) {
      uint4 vv = *(uint4*)&tile[(lrow + j)*72 + d8];
      float w = wsm[j];
      acc[0] += b2f((u16)(vv.x & 0xffff)) * w;
      acc[1] += b2f((u16)(vv.x >> 16))    * w;
      acc[2] += b2f((u16)(vv.y & 0xffff)) * w;
      acc[3] += b2f((u16)(vv.y >> 16))    * w;
      acc[4] += b2f((u16)(vv.z & 0xffff)) * w;
      acc[5] += b2f((u16)(vv.z >> 16))    * w;
      acc[6] += b2f((u16)(vv.w & 0xffff)) * w;
      acc[7] += b2f((u16)(vv.w >> 16))    * w;
    }
    size_t oi = ((size_t)(b*4096 + n0 + lrow))*512 + h*64 + d8;
    uint4 ov = *(uint4*)&outh[oi];
    uint4 nv;
    nv.x = (unsigned)f2b(b2f((u16)(ov.x & 0xffff)) + acc[0]) | ((unsigned)f2b(b2f((u16)(ov.x >> 16)) + acc[1]) << 16);
    nv.y = (unsigned)f2b(b2f((u16)(ov.y & 0xffff)) + acc[2]) | ((unsigned)f2b(b2f((u16)(ov.y >> 16)) + acc[3]) << 16);
    nv.z = (unsigned)f2b(b2f((u16)(ov.z & 0xffff)) + acc[4]) | ((unsigned)f2b(b2f((u16)(ov.z >> 16)) + acc[5]) << 16);
    nv.w = (unsigned)f2b(b2f((u16)(ov.w & 0xffff)) + acc[6]) | ((unsigned)f2b(b2f((u16)(ov.w >> 16)) + acc[7]) << 16);
    *(uint4*)&outh[oi] = nv;
  }
}

extern "C" void kernel_launch(void* const* d_in, const int* in_sizes, int n_in,
                              void* d_out, int out_size, void* d_ws, size_t ws_size,
                              hipStream_t stream) {
  const float* x      = (const float*)d_in[0];
  const float* norm_w = (const float*)d_in[1];
  const float* norm_b = (const float*)d_in[2];
  const float* w_qkv  = (const float*)d_in[3];
  const float* w_out  = (const float*)d_in[4];
  const float* b_out  = (const float*)d_in[5];
  const float* res_w  = (const float*)d_in[6];
  float* out = (float*)d_out;
  char* ws = (char*)d_ws;

  size_t off = 0;
  u16* xn    = (u16*)(ws + off); off += 16777216;
  u16* q     = (u16*)(ws + off); off += 16777216;
  u16* k     = (u16*)(ws + off); off += 16777216;
  u16* v     = (u16*)(ws + off); off += 16777216;
  u16* vT    = (u16*)(ws + off); off += 16777216;
  u16* ql    = (u16*)(ws + off); off += 1048576;
  u16* kl    = (u16*)(ws + off); off += 1048576;
  float* a2  = (float*)(ws + off); off += 8388608;
  u16* a2h   = (u16*)(ws + off); off += 4194304;
  u16* zA    = (u16*)(ws + off); off += 4194304;
  u16* zAT   = (u16*)(ws + off); off += 4194304;
  u16* zB    = (u16*)(ws + off); off += 4194304;
  u16* zBT   = (u16*)(ws + off); off += 4194304;
  u16* xz    = (u16*)(ws + off); off += 4194304;
  u16* e1T   = (u16*)(ws + off); off += 4194304;
  u16* e2T   = (u16*)(ws + off); off += 4194304;
  u16* e3T   = (u16*)(ws + off); off += 4194304;
  u16* a3vT  = (u16*)(ws + off); off += 1048576;
  u16* w2T   = (u16*)(ws + off); off += 1048576;
  u16* wqkvT = (u16*)(ws + off); off += 1572864;
  u16* woutT = (u16*)(ws + off); off += 524288;
  u16* outh  = (u16*)(ws + off); off += 16777216;
  float* po  = (float*)(ws + off); off += 16777216;
  float* pm  = (float*)(ws + off); off += 262144;
  float* pl  = (float*)(ws + off); off += 262144;
  unsigned* scal = (unsigned*)(ws + off); off += 8;

  ln_kernel<<<16384, 256, 0, stream>>>(x, norm_w, norm_b, xn);
  wcast_T<<<3072, 256, 0, stream>>>(w_qkv, wqkvT, 512, 1536);
  wcast_T<<<1024, 256, 0, stream>>>(w_out, woutT, 512, 512);
  qkv_mfma<<<dim3(12, 128), 256, 0, stream>>>(xn, wqkvT, q, k, v);
  vtrans<<<dim3(64, 32), 256, 0, stream>>>(v, vT);
  landmark_kernel<<<8192, 64, 0, stream>>>(q, k, ql, kl);
  hipMemsetAsync(scal, 0, 8, stream);
  sim2_mfma<<<32, 256, 0, stream>>>(ql, kl, a2, a2h, scal);
  z0_kernel<<<8192, 256, 0, stream>>>(a2, scal, zA, zAT);

  u16 *zc = zA, *zcT = zAT, *zn = zB, *znT = zBT;
  for (int it = 0; it < 6; it++) {
    bmm64<<<dim3(4,4,32), 256, 0, stream>>>(a2h, zcT, xz, nullptr, e1T, 256,256,256, 1.f, 0.f);
    bmm64<<<dim3(4,4,32), 256, 0, stream>>>(xz, e1T, nullptr, e2T, nullptr, 256,256,256, -1.f, 15.f);
    bmm64<<<dim3(4,4,32), 256, 0, stream>>>(xz, e2T, nullptr, e3T, nullptr, 256,256,256, -1.f, 13.f);
    bmm64<<<dim3(4,4,32), 256, 0, stream>>>(zc, e3T, zn, znT, nullptr, 256,256,256, 0.25f, 0.f);
    u16* tp;
    tp = zc; zc = zn; zn = tp;
    tp = zcT; zcT = znT; znT = tp;
  }

  flash_part<<<dim3(4, 8, 32), 256, 0, stream>>>(ql, k, vT, po, pm, pl);
  flash_merge<<<2048, 256, 0, stream>>>(po, pm, pl, a3vT);
  bmm64<<<dim3(1,4,32), 256, 0, stream>>>(zc, a3vT, nullptr, w2T, nullptr, 256, 64, 256, 1.f, 0.f);
  flash_a1<<<dim3(64, 32), 256, 0, stream>>>(q, kl, w2T, outh);
  conv_lds<<<dim3(32, 32), 256, 0, stream>>>(v, res_w, outh);
  out_mfma<<<dim3(4, 128), 256, 0, stream>>>(outh, woutT, b_out, x, out);
}